// Round 11
// baseline (338.595 us; speedup 1.0000x reference)
//
#include <hip/hip_runtime.h>

// GraphSAGE link predictor. f16 intermediates, XCD-sliced gather tables (coalesced
// slice writes), MFMA node GEMMs, swapped-MFMA edge MLP.
// Layouts:
//  slice f16 [8][N][8]:  xs (x -> g), ags (agg):  buf[(sl*N + node)*8 + d]
//  row   f16:            h1 [N][128], h2 [N][64] (f16buf)
// Pipeline:
//  kA: xs = f16(x) slices (coalesced) + deg hist
//  scan -> row ; cbinit ; k_coarse ; k_fine_sort (CSR srcs)
//  ags = segsum(xs[src])       (k_gather_slice, sl=bid&7 -> 1.6MB XCD-L2-resident)
//  h1 = (ags*inv)@Wl1 + xs@Wr1 + bl1   (MFMA MODE0, A/A2 slice, out row)
//  xs <- g = h1@Wl2                    (MFMA MODE1, out slice coalesced)
//  ags = segsum(xs[src])               (k_gather_slice)
//  h2 = h1@Wr2 + ags*inv + bl2         (MFMA MODE2, add slice, out row)
//  out[e] = relu((h2[s]*h2[d])@W1+b1)@W2+b2  (MFMA swapped D=[hid x edge])

typedef _Float16 f16x8 __attribute__((ext_vector_type(8)));
typedef float f32x4 __attribute__((ext_vector_type(4)));

union H4 { _Float16 h[4]; uint2 u; };
union H8 { _Float16 h[8]; uint4 u; };

// ---------------- kA: f32 -> f16 slices (coalesced) + deg histogram ----------------
__global__ __launch_bounds__(256) void kA_slice_hist(
    const float* __restrict__ x, _Float16* __restrict__ xs,
    const int* __restrict__ dst, int* __restrict__ deg, int N, int E) {
  int t = blockIdx.x * blockDim.x + threadIdx.x;
  if (t < N) {
    const float4* xv = (const float4*)(x + (size_t)t * 64);
#pragma unroll
    for (int sl = 0; sl < 8; sl++) {
      float4 a = xv[2 * sl], b = xv[2 * sl + 1];
      H8 p;
      p.h[0] = (_Float16)a.x; p.h[1] = (_Float16)a.y;
      p.h[2] = (_Float16)a.z; p.h[3] = (_Float16)a.w;
      p.h[4] = (_Float16)b.x; p.h[5] = (_Float16)b.y;
      p.h[6] = (_Float16)b.z; p.h[7] = (_Float16)b.w;
      *(uint4*)(xs + ((size_t)sl * N + t) * 8) = p.u;
    }
  }
  if (t < E) atomicAdd(&deg[dst[t]], 1);
}

// ---------------- scans ----------------
__global__ void k_scan1(const int* __restrict__ deg, int* __restrict__ ex,
                        int* __restrict__ bsum, int N) {
  __shared__ int sm[256];
  int t = threadIdx.x, i = blockIdx.x * 256 + t;
  int v = (i < N) ? deg[i] : 0;
  sm[t] = v;
  __syncthreads();
  for (int s = 1; s < 256; s <<= 1) {
    int a = (t >= s) ? sm[t - s] : 0;
    __syncthreads();
    sm[t] += a;
    __syncthreads();
  }
  if (i < N) ex[i] = sm[t] - v;
  if (t == 255) bsum[blockIdx.x] = sm[255];
}

__global__ void k_scan2(int* __restrict__ bsum, int nb) {
  __shared__ int sm[1024];
  int t = threadIdx.x;
  int v = (t < nb) ? bsum[t] : 0;
  sm[t] = v;
  __syncthreads();
  for (int s = 1; s < 1024; s <<= 1) {
    int a = (t >= s) ? sm[t - s] : 0;
    __syncthreads();
    sm[t] += a;
    __syncthreads();
  }
  if (t < nb) bsum[t] = sm[t] - v;
}

__global__ void k_scan3(const int* __restrict__ bsum, int* __restrict__ row,
                        const int* __restrict__ ex, int N, int E) {
  int i = blockIdx.x * blockDim.x + threadIdx.x;
  if (i < N) row[i] = ex[i] + bsum[i >> 8];
  if (i == 0) row[N] = E;
}

__global__ void k_cbinit(const int* __restrict__ row, int* __restrict__ cbcursor,
                         int N, int ncb) {
  int b = threadIdx.x + blockIdx.x * blockDim.x;
  if (b < ncb) {
    int node = b << 8;
    cbcursor[b] = row[node < N ? node : N];
  }
}

// ---------------- pass A: bucket edges by dst>>8 into packed u64 streams ----------
__global__ __launch_bounds__(256) void k_coarse(
    const int* __restrict__ src, const int* __restrict__ dst,
    int* __restrict__ cbcursor, unsigned long long* __restrict__ ep, int E) {
  __shared__ int lh[512];
  const int t = threadIdx.x;
  const int chunk = (E + gridDim.x - 1) / gridDim.x;
  const int e0 = blockIdx.x * chunk;
  const int e1 = min(e0 + chunk, E);
  lh[t] = 0; lh[t + 256] = 0;
  __syncthreads();
  for (int e = e0 + t; e < e1; e += 256)
    atomicAdd(&lh[dst[e] >> 8], 1);
  __syncthreads();
  {
    int c0 = lh[t], c1 = lh[t + 256];
    int b0 = c0 ? atomicAdd(&cbcursor[t], c0) : 0;
    int b1 = c1 ? atomicAdd(&cbcursor[t + 256], c1) : 0;
    __syncthreads();
    lh[t] = b0; lh[t + 256] = b1;
  }
  __syncthreads();
  for (int e = e0 + t; e < e1; e += 256) {
    int d = dst[e];
    int pos = atomicAdd(&lh[d >> 8], 1);
    ep[pos] = ((unsigned long long)d << 32) | (unsigned)src[e];
  }
}

// ---------------- pass B: per-bucket LDS count-sort -> coalesced srcs ----------
#define FS_CAP 4608
__global__ __launch_bounds__(256) void k_fine_sort(
    const unsigned long long* __restrict__ ep, const int* __restrict__ row,
    int* __restrict__ srcs, int N, int E) {
  __shared__ int cnt[256];
  __shared__ int cur[256];
  __shared__ int sm[256];
  __shared__ int stage[FS_CAP];
  const int b = blockIdx.x;
  const int t = threadIdx.x;
  const int n0 = b << 8;
  const int n1 = min(n0 + 256, N);
  const int beg = row[n0];
  const int end = row[n1];
  const int M = end - beg;

  cnt[t] = 0;
  __syncthreads();
  for (int i = beg + t; i < end; i += 256) {
    int loc = (int)(ep[i] >> 32) & 255;
    atomicAdd(&cnt[loc], 1);
  }
  __syncthreads();
  int v = cnt[t];
  sm[t] = v;
  __syncthreads();
  for (int s = 1; s < 256; s <<= 1) {
    int a = (t >= s) ? sm[t - s] : 0;
    __syncthreads();
    sm[t] += a;
    __syncthreads();
  }
  cur[t] = sm[t] - v;
  __syncthreads();
  for (int i = beg + t; i < end; i += 256) {
    unsigned long long p = ep[i];
    int loc = (int)(p >> 32) & 255;
    int pos = atomicAdd(&cur[loc], 1);
    if (pos < FS_CAP) stage[pos] = (int)(unsigned)p;
    else srcs[beg + pos] = (int)(unsigned)p;   // statistically never
  }
  __syncthreads();
  const int m = min(M, FS_CAP);
  for (int i = t; i < m; i += 256) srcs[beg + i] = stage[i];
}

// ---------------- sliced aggregation: sl = bid&7, 1 thread/node, 16B rows --------
__global__ __launch_bounds__(256) void k_gather_slice(
    const _Float16* __restrict__ xs, const int* __restrict__ row,
    const int* __restrict__ srcs, _Float16* __restrict__ ags, int N) {
  const int sl = blockIdx.x & 7;
  const int node = (blockIdx.x >> 3) * 256 + threadIdx.x;
  if (node >= N) return;
  const _Float16* xsl = xs + (size_t)sl * N * 8;
  int beg = row[node], end = row[node + 1];
  float acc[8];
#pragma unroll
  for (int i = 0; i < 8; i++) acc[i] = 0.f;
  int k = beg;
  for (; k + 3 < end; k += 4) {
    int s0 = srcs[k], s1 = srcs[k + 1], s2 = srcs[k + 2], s3 = srcs[k + 3];
    H8 a, b, c, d;
    a.u = *(const uint4*)(xsl + (size_t)s0 * 8);
    b.u = *(const uint4*)(xsl + (size_t)s1 * 8);
    c.u = *(const uint4*)(xsl + (size_t)s2 * 8);
    d.u = *(const uint4*)(xsl + (size_t)s3 * 8);
#pragma unroll
    for (int i = 0; i < 8; i++)
      acc[i] += ((float)a.h[i] + (float)b.h[i]) + ((float)c.h[i] + (float)d.h[i]);
  }
  for (; k < end; k++) {
    H8 a; a.u = *(const uint4*)(xsl + (size_t)srcs[k] * 8);
#pragma unroll
    for (int i = 0; i < 8; i++) acc[i] += (float)a.h[i];
  }
  H8 o;
#pragma unroll
  for (int i = 0; i < 8; i++) o.h[i] = (_Float16)acc[i];
  *(uint4*)(ags + ((size_t)sl * N + node) * 8) = o.u;
}

// ---------------- MFMA node GEMM ----------------
// MODE 0: acc = A@W (slice A); *= inv ; += A2@Wb (slice A2) ; += bias ; row out
// MODE 1: acc = A@W (row A)                                 ; slice out (coalesced)
// MODE 2: acc = A@W (row A) ; += add(slice)*inv + bias      ; row out
template <int K, int J, int MODE, int ASLICE, int OSLICE>
__global__ __launch_bounds__(256) void k_node_mfma(
    const _Float16* __restrict__ A, const _Float16* __restrict__ A2,
    const float* __restrict__ W, const float* __restrict__ Wb,
    const float* __restrict__ bias, const _Float16* __restrict__ add64,
    const int* __restrict__ deg, _Float16* __restrict__ outp, int N) {
  constexpr int KS = K / 32;   // k-steps (2 or 4)
  constexpr int TT = J / 16;   // col tiles (8 or 4)
  constexpr int RU4 = J / 8;   // uint4 per output row
  __shared__ _Float16 ostage[4][16][J + 8];

  const int w = threadIdx.x >> 6;
  const int l = threadIdx.x & 63;
  const int col = l & 15;
  const int kb8 = (l >> 4) * 8;
  const int nb = blockIdx.x * 64 + w * 16;
  const int nodeA = min(nb + col, N - 1);

  auto loadA = [&](const _Float16* __restrict__ S, int s) -> f16x8 {
    if constexpr (ASLICE)
      return *(const f16x8*)(S + ((size_t)(s * 4 + (kb8 >> 3)) * N + nodeA) * 8);
    else
      return *(const f16x8*)(S + (size_t)nodeA * K + s * 32 + kb8);
  };

  // preload W fragments (f32 -> f16): lane supplies B[k=kb8+e][j=tt*16+col]
  f16x8 wf[TT][KS];
#pragma unroll
  for (int tt = 0; tt < TT; tt++)
#pragma unroll
    for (int s = 0; s < KS; s++) {
      f16x8 v;
#pragma unroll
      for (int e = 0; e < 8; e++)
        v[e] = (_Float16)W[(size_t)(s * 32 + kb8 + e) * J + tt * 16 + col];
      wf[tt][s] = v;
    }

  f16x8 af[KS];
#pragma unroll
  for (int s = 0; s < KS; s++) af[s] = loadA(A, s);

  f32x4 acc[TT];
#pragma unroll
  for (int tt = 0; tt < TT; tt++) {
    f32x4 a = {0.f, 0.f, 0.f, 0.f};
#pragma unroll
    for (int s = 0; s < KS; s++)
      a = __builtin_amdgcn_mfma_f32_16x16x32_f16(af[s], wf[tt][s], a, 0, 0, 0);
    acc[tt] = a;
  }

  if constexpr (MODE == 0) {
    float inv[4];
#pragma unroll
    for (int reg = 0; reg < 4; reg++) {
      int nd = min(nb + (l >> 4) * 4 + reg, N - 1);
      inv[reg] = 1.0f / fmaxf((float)deg[nd], 1.0f);
    }
#pragma unroll
    for (int tt = 0; tt < TT; tt++)
#pragma unroll
      for (int reg = 0; reg < 4; reg++) acc[tt][reg] *= inv[reg];

    f16x8 wfb[TT][KS];
#pragma unroll
    for (int tt = 0; tt < TT; tt++)
#pragma unroll
      for (int s = 0; s < KS; s++) {
        f16x8 v;
#pragma unroll
        for (int e = 0; e < 8; e++)
          v[e] = (_Float16)Wb[(size_t)(s * 32 + kb8 + e) * J + tt * 16 + col];
        wfb[tt][s] = v;
      }
#pragma unroll
    for (int s = 0; s < KS; s++) af[s] = loadA(A2, s);
#pragma unroll
    for (int tt = 0; tt < TT; tt++)
#pragma unroll
      for (int s = 0; s < KS; s++)
        acc[tt] = __builtin_amdgcn_mfma_f32_16x16x32_f16(af[s], wfb[tt][s], acc[tt], 0, 0, 0);

#pragma unroll
    for (int tt = 0; tt < TT; tt++) {
      float bl = bias[tt * 16 + col];
#pragma unroll
      for (int reg = 0; reg < 4; reg++) acc[tt][reg] += bl;
    }
  }

  if constexpr (MODE == 2) {
    float inv[4];
    int ndc[4];
#pragma unroll
    for (int reg = 0; reg < 4; reg++) {
      ndc[reg] = min(nb + (l >> 4) * 4 + reg, N - 1);
      inv[reg] = 1.0f / fmaxf((float)deg[ndc[reg]], 1.0f);
    }
#pragma unroll
    for (int tt = 0; tt < TT; tt++) {
      float bl = bias[tt * 16 + col];
      int jsl = tt * 2 + (col >> 3);
      int jd  = col & 7;
#pragma unroll
      for (int reg = 0; reg < 4; reg++) {
        float ad = (float)add64[((size_t)jsl * N + ndc[reg]) * 8 + jd];
        acc[tt][reg] += ad * inv[reg] + bl;
      }
    }
  }

  // stage D -> LDS (node-major), then coalesced global stores
#pragma unroll
  for (int tt = 0; tt < TT; tt++)
#pragma unroll
    for (int reg = 0; reg < 4; reg++)
      ostage[w][(l >> 4) * 4 + reg][tt * 16 + col] = (_Float16)acc[tt][reg];
  __syncthreads();
  if constexpr (OSLICE) {
    // J==64: 16 nodes x 8 slices = 128 uint4; consecutive lanes -> consecutive nodes
#pragma unroll
    for (int i = 0; i < 2; i++) {
      int idx = i * 64 + l;
      int q = idx >> 4, r = idx & 15;
      int gn = nb + r;
      if (gn < N)
        *(uint4*)(outp + ((size_t)q * N + gn) * 8) =
            *(const uint4*)(&ostage[w][r][q * 8]);
    }
  } else {
#pragma unroll
    for (int i = 0; i < J / 32; i++) {
      int idx = i * 64 + l;
      int r = idx / RU4, q = idx % RU4;
      int gn = nb + r;
      if (gn < N)
        *(uint4*)(outp + (size_t)gn * J + q * 8) =
            *(const uint4*)(&ostage[w][r][q * 8]);
    }
  }
}

// ---------------- edge MLP: swapped MFMA, D=[hid x edge], b1 in C-init ----------
__global__ __launch_bounds__(256) void k_edge_mfma(
    const _Float16* __restrict__ h2, const int* __restrict__ src,
    const int* __restrict__ dst,
    const float* __restrict__ W1, const float* __restrict__ W2,
    const float* __restrict__ b1, const float* __restrict__ b2,
    float* __restrict__ out, int E) {
  const int gtid = blockIdx.x * blockDim.x + threadIdx.x;
  const int wave = gtid >> 6;
  const int nwaves = (gridDim.x * blockDim.x) >> 6;
  const int l = threadIdx.x & 63;
  const int col = l & 15;
  const int kb = (l >> 4) * 8;
  const int hb = (l >> 4) * 4;
  const int ngroups = (E + 15) / 16;
  const int gpw = (ngroups + nwaves - 1) / nwaves;
  const int g0 = wave * gpw;
  const int g1 = min(g0 + gpw, ngroups);
  if (g0 >= ngroups) return;

  f16x8 afrag[8][2];
#pragma unroll
  for (int tt = 0; tt < 8; tt++)
#pragma unroll
    for (int s = 0; s < 2; s++) {
      f16x8 bf;
#pragma unroll
      for (int e = 0; e < 8; e++)
        bf[e] = (_Float16)W1[(size_t)(s * 32 + kb + e) * 128 + tt * 16 + col];
      afrag[tt][s] = bf;
    }
  float4 c0[8], w2v[8];
#pragma unroll
  for (int tt = 0; tt < 8; tt++) {
    int hbase = tt * 16 + hb;
    c0[tt]  = make_float4(b1[hbase], b1[hbase + 1], b1[hbase + 2], b1[hbase + 3]);
    w2v[tt] = make_float4(W2[hbase], W2[hbase + 1], W2[hbase + 2], W2[hbase + 3]);
  }
  const float b2v = b2[0];

  auto ldrows = [&](int g, f16x8& a0, f16x8& a1) {
    int pos = g * 16 + col;
    if (pos >= E) pos = E - 1;
    int sp = src[pos], dp = dst[pos];
    f16x8 as0 = *(const f16x8*)(h2 + (size_t)sp * 64 + kb);
    f16x8 ad0 = *(const f16x8*)(h2 + (size_t)dp * 64 + kb);
    f16x8 as1 = *(const f16x8*)(h2 + (size_t)sp * 64 + 32 + kb);
    f16x8 ad1 = *(const f16x8*)(h2 + (size_t)dp * 64 + 32 + kb);
    a0 = as0 * ad0;
    a1 = as1 * ad1;
  };

  auto compute = [&](int g, f16x8 a0, f16x8 a1) {
    float psum = 0.f;
#pragma unroll
    for (int tt = 0; tt < 8; tt++) {
      f32x4 acc = {c0[tt].x, c0[tt].y, c0[tt].z, c0[tt].w};
      acc = __builtin_amdgcn_mfma_f32_16x16x32_f16(afrag[tt][0], a0, acc, 0, 0, 0);
      acc = __builtin_amdgcn_mfma_f32_16x16x32_f16(afrag[tt][1], a1, acc, 0, 0, 0);
      psum += fmaxf(acc[0], 0.f) * w2v[tt].x + fmaxf(acc[1], 0.f) * w2v[tt].y
            + fmaxf(acc[2], 0.f) * w2v[tt].z + fmaxf(acc[3], 0.f) * w2v[tt].w;
    }
    psum += __shfl_xor(psum, 16, 64);
    psum += __shfl_xor(psum, 32, 64);
    if (l < 16) {
      int epos = g * 16 + l;
      if (epos < E) out[epos] = psum + b2v;
    }
  };

  f16x8 a0, a1, na0, na1;
  ldrows(g0, a0, a1);
  for (int g = g0; g < g1; g++) {
    if (g + 1 < g1) ldrows(g + 1, na0, na1);
    compute(g, a0, a1);
    a0 = na0; a1 = na1;
  }
}

// ---------------- launch ----------------
extern "C" void kernel_launch(void* const* d_in, const int* in_sizes, int n_in,
                              void* d_out, int out_size, void* d_ws, size_t ws_size,
                              hipStream_t stream) {
  const float* x   = (const float*)d_in[0];
  const int*   ei  = (const int*)d_in[1];
  const float* Wl1 = (const float*)d_in[2];
  const float* bl1 = (const float*)d_in[3];
  const float* Wr1 = (const float*)d_in[4];
  const float* Wl2 = (const float*)d_in[5];
  const float* bl2 = (const float*)d_in[6];
  const float* Wr2 = (const float*)d_in[7];
  const float* W1  = (const float*)d_in[8];
  const float* b1  = (const float*)d_in[9];
  const float* W2  = (const float*)d_in[10];
  const float* b2  = (const float*)d_in[11];
  const int N = in_sizes[0] / 64;
  const int E = in_sizes[1] / 2;
  const int* src = ei;
  const int* dstp = ei + E;

  char* w = (char*)d_ws;
  size_t off = 0;
  auto alloc = [&](size_t bytes) -> void* {
    void* p = w + off;
    off = (off + bytes + 255) & ~(size_t)255;
    return p;
  };
  int*      deg      = (int*)alloc((size_t)N * 4);
  int*      row      = (int*)alloc((size_t)(N + 1) * 4);
  int*      ex       = (int*)alloc((size_t)N * 4);
  int*      bsum     = (int*)alloc(1024 * 4);
  int*      cbcursor = (int*)alloc(512 * 4);
  int*      srcs     = (int*)alloc((size_t)E * 4);
  unsigned long long* ep = (unsigned long long*)alloc((size_t)E * 8);
  _Float16* f16buf   = (_Float16*)alloc((size_t)N * 64 * 2);   // h2 (row)
  _Float16* xs       = (_Float16*)alloc((size_t)N * 64 * 2);   // x slices -> g slices
  _Float16* ags      = (_Float16*)alloc((size_t)N * 64 * 2);   // agg slices
  _Float16* h1_16    = (_Float16*)alloc((size_t)N * 128 * 2);

  const int ncb = (N + 255) >> 8;

  hipMemsetAsync(deg, 0, (size_t)N * 4, stream);
  int kag = (max(N, E) + 255) / 256;
  kA_slice_hist<<<kag, 256, 0, stream>>>(x, xs, dstp, deg, N, E);
  int nb = (N + 255) / 256;
  k_scan1<<<nb, 256, 0, stream>>>(deg, ex, bsum, N);
  k_scan2<<<1, 1024, 0, stream>>>(bsum, nb);
  k_scan3<<<nb, 256, 0, stream>>>(bsum, row, ex, N, E);
  k_cbinit<<<2, 256, 0, stream>>>(row, cbcursor, N, ncb);
  k_coarse<<<256, 256, 0, stream>>>(src, dstp, cbcursor, ep, E);
  k_fine_sort<<<ncb, 256, 0, stream>>>(ep, row, srcs, N, E);

  int ngrid = (N + 63) / 64;
  int sgrid = 8 * ((N + 255) / 256);
  k_gather_slice<<<sgrid, 256, 0, stream>>>(xs, row, srcs, ags, N);
  k_node_mfma<64, 128, 0, 1, 0><<<ngrid, 256, 0, stream>>>(
      ags, xs, Wl1, Wr1, bl1, nullptr, deg, h1_16, N);
  k_node_mfma<128, 64, 1, 0, 1><<<ngrid, 256, 0, stream>>>(
      h1_16, nullptr, Wl2, nullptr, nullptr, nullptr, nullptr, xs, N);
  k_gather_slice<<<sgrid, 256, 0, stream>>>(xs, row, srcs, ags, N);
  k_node_mfma<128, 64, 2, 0, 0><<<ngrid, 256, 0, stream>>>(
      h1_16, nullptr, Wr2, nullptr, bl2, ags, deg, f16buf, N);
  k_edge_mfma<<<4096, 256, 0, stream>>>(f16buf, src, dstp, W1, W2, b1, b2,
                                        (float*)d_out, E);
}

// Round 12
// 267.758 us; speedup vs baseline: 1.2646x; 1.2646x over previous
//
#include <hip/hip_runtime.h>

// GraphSAGE link predictor. f16 row-major intermediates, 2-pass CSR bucket,
// MFMA node GEMMs (h1+g fused), swapped-MFMA edge MLP.
// Pipeline:
//  kA: x16 = f16(x) + deg hist (fused)
//  scan (cbinit fused into scan3) ; k_coarse ; k_fine_sort (CSR srcs)
//  agg16 = f16(segsum(x16[src]))            (gather, 8 lanes/row, f32 accum)
//  k_h1g: h1 = (agg*inv)@Wl1 + x16@Wr1 + bl1 ; g = h1@Wl2 (LDS-fused, MFMA)
//  agg16 = f16(segsum(g[src]))              (gather)
//  h2 = h1@Wr2 + agg*inv + bl2              (MFMA MODE2, f16 out)
//  out[e] = relu((h2[s]*h2[d])@W1+b1)@W2+b2 (MFMA swapped D=[hid x edge])

typedef _Float16 f16x8 __attribute__((ext_vector_type(8)));
typedef float f32x4 __attribute__((ext_vector_type(4)));

union H4 { _Float16 h[4]; uint2 u; };
union H8 { _Float16 h[8]; uint4 u; };

__device__ inline uint2 pack4(float4 v) {
  H4 p;
  p.h[0] = (_Float16)v.x; p.h[1] = (_Float16)v.y;
  p.h[2] = (_Float16)v.z; p.h[3] = (_Float16)v.w;
  return p.u;
}

// ---------------- kA: f32->f16 convert + deg histogram ----------------
__global__ void kA_convert_hist(const float* __restrict__ x, _Float16* __restrict__ x16,
                                const int* __restrict__ dst, int* __restrict__ deg,
                                int n4, int E) {
  int t = blockIdx.x * blockDim.x + threadIdx.x;
  if (t < n4) {
    float4 v = ((const float4*)x)[t];
    ((uint2*)x16)[t] = pack4(v);
  }
  if (t < E) atomicAdd(&deg[dst[t]], 1);
}

// ---------------- scans ----------------
__global__ void k_scan1(const int* __restrict__ deg, int* __restrict__ ex,
                        int* __restrict__ bsum, int N) {
  __shared__ int sm[256];
  int t = threadIdx.x, i = blockIdx.x * 256 + t;
  int v = (i < N) ? deg[i] : 0;
  sm[t] = v;
  __syncthreads();
  for (int s = 1; s < 256; s <<= 1) {
    int a = (t >= s) ? sm[t - s] : 0;
    __syncthreads();
    sm[t] += a;
    __syncthreads();
  }
  if (i < N) ex[i] = sm[t] - v;
  if (t == 255) bsum[blockIdx.x] = sm[255];
}

__global__ void k_scan2(int* __restrict__ bsum, int nb) {
  __shared__ int sm[1024];
  int t = threadIdx.x;
  int v = (t < nb) ? bsum[t] : 0;
  sm[t] = v;
  __syncthreads();
  for (int s = 1; s < 1024; s <<= 1) {
    int a = (t >= s) ? sm[t - s] : 0;
    __syncthreads();
    sm[t] += a;
    __syncthreads();
  }
  if (t < nb) bsum[t] = sm[t] - v;
}

// scan3 + cbinit fused: row[] final values + coarse-bucket cursors
__global__ void k_scan3(const int* __restrict__ bsum, int* __restrict__ row,
                        const int* __restrict__ ex, int* __restrict__ cbcursor,
                        int N, int E) {
  int i = blockIdx.x * blockDim.x + threadIdx.x;
  if (i < N) {
    int v = ex[i] + bsum[i >> 8];
    row[i] = v;
    if ((i & 255) == 0) cbcursor[i >> 8] = v;
  }
  if (i == 0) row[N] = E;
}

// ---------------- pass A: bucket edges by dst>>8 into packed u64 streams ----------
__global__ __launch_bounds__(256) void k_coarse(
    const int* __restrict__ src, const int* __restrict__ dst,
    int* __restrict__ cbcursor, unsigned long long* __restrict__ ep, int E) {
  __shared__ int lh[512];
  const int t = threadIdx.x;
  const int chunk = (E + gridDim.x - 1) / gridDim.x;
  const int e0 = blockIdx.x * chunk;
  const int e1 = min(e0 + chunk, E);
  lh[t] = 0; lh[t + 256] = 0;
  __syncthreads();
  for (int e = e0 + t; e < e1; e += 256)
    atomicAdd(&lh[dst[e] >> 8], 1);
  __syncthreads();
  {
    int c0 = lh[t], c1 = lh[t + 256];
    int b0 = c0 ? atomicAdd(&cbcursor[t], c0) : 0;
    int b1 = c1 ? atomicAdd(&cbcursor[t + 256], c1) : 0;
    __syncthreads();
    lh[t] = b0; lh[t + 256] = b1;
  }
  __syncthreads();
  for (int e = e0 + t; e < e1; e += 256) {
    int d = dst[e];
    int pos = atomicAdd(&lh[d >> 8], 1);
    ep[pos] = ((unsigned long long)d << 32) | (unsigned)src[e];
  }
}

// ---------------- pass B: per-bucket LDS count-sort -> coalesced srcs ----------
#define FS_CAP 4608
__global__ __launch_bounds__(256) void k_fine_sort(
    const unsigned long long* __restrict__ ep, const int* __restrict__ row,
    int* __restrict__ srcs, int N, int E) {
  __shared__ int cnt[256];
  __shared__ int cur[256];
  __shared__ int sm[256];
  __shared__ int stage[FS_CAP];
  const int b = blockIdx.x;
  const int t = threadIdx.x;
  const int n0 = b << 8;
  const int n1 = min(n0 + 256, N);
  const int beg = row[n0];
  const int end = row[n1];
  const int M = end - beg;

  cnt[t] = 0;
  __syncthreads();
  for (int i = beg + t; i < end; i += 256) {
    int loc = (int)(ep[i] >> 32) & 255;
    atomicAdd(&cnt[loc], 1);
  }
  __syncthreads();
  int v = cnt[t];
  sm[t] = v;
  __syncthreads();
  for (int s = 1; s < 256; s <<= 1) {
    int a = (t >= s) ? sm[t - s] : 0;
    __syncthreads();
    sm[t] += a;
    __syncthreads();
  }
  cur[t] = sm[t] - v;
  __syncthreads();
  for (int i = beg + t; i < end; i += 256) {
    unsigned long long p = ep[i];
    int loc = (int)(p >> 32) & 255;
    int pos = atomicAdd(&cur[loc], 1);
    if (pos < FS_CAP) stage[pos] = (int)(unsigned)p;
    else srcs[beg + pos] = (int)(unsigned)p;   // statistically never
  }
  __syncthreads();
  const int m = min(M, FS_CAP);
  for (int i = t; i < m; i += 256) srcs[beg + i] = stage[i];
}

// ---------------- aggregation: 8 lanes/row (16B each), unroll 4, f16 out --------
__global__ __launch_bounds__(256) void k_gather16(
    const _Float16* __restrict__ feat, const int* __restrict__ row,
    const int* __restrict__ srcs, _Float16* __restrict__ agg, int N) {
  int tid = blockIdx.x * blockDim.x + threadIdx.x;
  int node = tid >> 3, slot = tid & 7;
  if (node >= N) return;
  int beg = row[node], end = row[node + 1];
  float acc[8];
#pragma unroll
  for (int i = 0; i < 8; i++) acc[i] = 0.f;
  int k = beg;
  for (; k + 3 < end; k += 4) {
    int s0 = srcs[k], s1 = srcs[k + 1], s2 = srcs[k + 2], s3 = srcs[k + 3];
    H8 a, b, c, d;
    a.u = *(const uint4*)(feat + (size_t)s0 * 64 + slot * 8);
    b.u = *(const uint4*)(feat + (size_t)s1 * 64 + slot * 8);
    c.u = *(const uint4*)(feat + (size_t)s2 * 64 + slot * 8);
    d.u = *(const uint4*)(feat + (size_t)s3 * 64 + slot * 8);
#pragma unroll
    for (int i = 0; i < 8; i++)
      acc[i] += ((float)a.h[i] + (float)b.h[i]) + ((float)c.h[i] + (float)d.h[i]);
  }
  for (; k < end; k++) {
    H8 a; a.u = *(const uint4*)(feat + (size_t)srcs[k] * 64 + slot * 8);
#pragma unroll
    for (int i = 0; i < 8; i++) acc[i] += (float)a.h[i];
  }
  H8 o;
#pragma unroll
  for (int i = 0; i < 8; i++) o.h[i] = (_Float16)acc[i];
  *(uint4*)(agg + (size_t)node * 64 + slot * 8) = o.u;
}

// ---------------- fused h1 + g MFMA kernel ----------------
// h1 = (agg@Wl1)*inv + x16@Wr1 + bl1  -> h1o [N][128] (row) + LDS
// g  = h1@Wl2                          -> g16 [N][64]  (row; may alias x16 —
//                                         safe: reads/writes are node-disjoint
//                                         per block; clamped reads feed only
//                                         discarded outputs)
__global__ __launch_bounds__(256) void k_h1g_mfma(
    const _Float16* __restrict__ agg, const _Float16* __restrict__ x16,
    const float* __restrict__ Wl1, const float* __restrict__ Wr1,
    const float* __restrict__ bl1, const float* __restrict__ Wl2,
    const int* __restrict__ deg,
    _Float16* __restrict__ h1o, _Float16* __restrict__ g16, int N) {
  __shared__ _Float16 ostage[4][16][136];
  const int w = threadIdx.x >> 6;
  const int l = threadIdx.x & 63;
  const int col = l & 15;
  const int kb8 = (l >> 4) * 8;
  const int nb = blockIdx.x * 64 + w * 16;
  const int nodeA = min(nb + col, N - 1);

  // ---- phase 1: acc = agg @ Wl1 ----
  f16x8 wf[8][2];
#pragma unroll
  for (int tt = 0; tt < 8; tt++)
#pragma unroll
    for (int s = 0; s < 2; s++) {
      f16x8 v;
#pragma unroll
      for (int e = 0; e < 8; e++)
        v[e] = (_Float16)Wl1[(size_t)(s * 32 + kb8 + e) * 128 + tt * 16 + col];
      wf[tt][s] = v;
    }
  f16x8 af[2];
#pragma unroll
  for (int s = 0; s < 2; s++)
    af[s] = *(const f16x8*)(agg + (size_t)nodeA * 64 + s * 32 + kb8);

  f32x4 acc[8];
#pragma unroll
  for (int tt = 0; tt < 8; tt++) {
    f32x4 a = {0.f, 0.f, 0.f, 0.f};
#pragma unroll
    for (int s = 0; s < 2; s++)
      a = __builtin_amdgcn_mfma_f32_16x16x32_f16(af[s], wf[tt][s], a, 0, 0, 0);
    acc[tt] = a;
  }

  // ---- mean scaling ----
  float inv[4];
#pragma unroll
  for (int reg = 0; reg < 4; reg++) {
    int nd = min(nb + (l >> 4) * 4 + reg, N - 1);
    inv[reg] = 1.0f / fmaxf((float)deg[nd], 1.0f);
  }
#pragma unroll
  for (int tt = 0; tt < 8; tt++)
#pragma unroll
    for (int reg = 0; reg < 4; reg++) acc[tt][reg] *= inv[reg];

  // ---- phase 2: acc += x16 @ Wr1 ; + bl1 ----
  f16x8 wfb[8][2];
#pragma unroll
  for (int tt = 0; tt < 8; tt++)
#pragma unroll
    for (int s = 0; s < 2; s++) {
      f16x8 v;
#pragma unroll
      for (int e = 0; e < 8; e++)
        v[e] = (_Float16)Wr1[(size_t)(s * 32 + kb8 + e) * 128 + tt * 16 + col];
      wfb[tt][s] = v;
    }
#pragma unroll
  for (int s = 0; s < 2; s++)
    af[s] = *(const f16x8*)(x16 + (size_t)nodeA * 64 + s * 32 + kb8);
#pragma unroll
  for (int tt = 0; tt < 8; tt++)
#pragma unroll
    for (int s = 0; s < 2; s++)
      acc[tt] = __builtin_amdgcn_mfma_f32_16x16x32_f16(af[s], wfb[tt][s], acc[tt], 0, 0, 0);
#pragma unroll
  for (int tt = 0; tt < 8; tt++) {
    float bl = bl1[tt * 16 + col];
#pragma unroll
    for (int reg = 0; reg < 4; reg++) acc[tt][reg] += bl;
  }

  // ---- stage h1 in LDS + coalesced global h1 store ----
#pragma unroll
  for (int tt = 0; tt < 8; tt++)
#pragma unroll
    for (int reg = 0; reg < 4; reg++)
      ostage[w][(l >> 4) * 4 + reg][tt * 16 + col] = (_Float16)acc[tt][reg];
  __syncthreads();
#pragma unroll
  for (int i = 0; i < 4; i++) {
    int idx = i * 64 + l;
    int r = idx >> 4, q = idx & 15;
    int gn = nb + r;
    if (gn < N)
      *(uint4*)(h1o + (size_t)gn * 128 + q * 8) = *(const uint4*)(&ostage[w][r][q * 8]);
  }

  // ---- g phase: g = h1 @ Wl2 (A-frags from own wave's LDS partition) ----
  f16x8 wf2[4][4];
#pragma unroll
  for (int tt = 0; tt < 4; tt++)
#pragma unroll
    for (int s = 0; s < 4; s++) {
      f16x8 v;
#pragma unroll
      for (int e = 0; e < 8; e++)
        v[e] = (_Float16)Wl2[(size_t)(s * 32 + kb8 + e) * 64 + tt * 16 + col];
      wf2[tt][s] = v;
    }
  f16x8 af2[4];
#pragma unroll
  for (int s = 0; s < 4; s++)
    af2[s] = *(const f16x8*)(&ostage[w][col][s * 32 + kb8]);

  f32x4 acc2[4];
#pragma unroll
  for (int tt = 0; tt < 4; tt++) {
    f32x4 a = {0.f, 0.f, 0.f, 0.f};
#pragma unroll
    for (int s = 0; s < 4; s++)
      a = __builtin_amdgcn_mfma_f32_16x16x32_f16(af2[s], wf2[tt][s], a, 0, 0, 0);
    acc2[tt] = a;
  }

  // stage g (values depend on af2 reads -> no LDS race) + coalesced store
#pragma unroll
  for (int tt = 0; tt < 4; tt++)
#pragma unroll
    for (int reg = 0; reg < 4; reg++)
      ostage[w][(l >> 4) * 4 + reg][tt * 16 + col] = (_Float16)acc2[tt][reg];
  __syncthreads();
#pragma unroll
  for (int i = 0; i < 2; i++) {
    int idx = i * 64 + l;
    int r = idx >> 3, q = idx & 7;
    int gn = nb + r;
    if (gn < N)
      *(uint4*)(g16 + (size_t)gn * 64 + q * 8) = *(const uint4*)(&ostage[w][r][q * 8]);
  }
}

// ---------------- MFMA node GEMM (h2): out = A@W + add64*inv + bias ----------------
__global__ __launch_bounds__(256) void k_h2_mfma(
    const _Float16* __restrict__ A, const float* __restrict__ W,
    const float* __restrict__ bias, const _Float16* __restrict__ add64,
    const int* __restrict__ deg, _Float16* __restrict__ outp, int N) {
  constexpr int KS = 4;   // K=128
  constexpr int TT = 4;   // J=64
  __shared__ _Float16 ostage[4][16][72];

  const int w = threadIdx.x >> 6;
  const int l = threadIdx.x & 63;
  const int col = l & 15;
  const int kb8 = (l >> 4) * 8;
  const int nb = blockIdx.x * 64 + w * 16;
  const int nodeA = min(nb + col, N - 1);

  f16x8 wf[TT][KS];
#pragma unroll
  for (int tt = 0; tt < TT; tt++)
#pragma unroll
    for (int s = 0; s < KS; s++) {
      f16x8 v;
#pragma unroll
      for (int e = 0; e < 8; e++)
        v[e] = (_Float16)W[(size_t)(s * 32 + kb8 + e) * 64 + tt * 16 + col];
      wf[tt][s] = v;
    }
  f16x8 af[KS];
#pragma unroll
  for (int s = 0; s < KS; s++)
    af[s] = *(const f16x8*)(A + (size_t)nodeA * 128 + s * 32 + kb8);

  f32x4 acc[TT];
#pragma unroll
  for (int tt = 0; tt < TT; tt++) {
    f32x4 a = {0.f, 0.f, 0.f, 0.f};
#pragma unroll
    for (int s = 0; s < KS; s++)
      a = __builtin_amdgcn_mfma_f32_16x16x32_f16(af[s], wf[tt][s], a, 0, 0, 0);
    acc[tt] = a;
  }

  float inv[4];
  int ndc[4];
#pragma unroll
  for (int reg = 0; reg < 4; reg++) {
    ndc[reg] = min(nb + (l >> 4) * 4 + reg, N - 1);
    inv[reg] = 1.0f / fmaxf((float)deg[ndc[reg]], 1.0f);
  }
#pragma unroll
  for (int tt = 0; tt < TT; tt++) {
    float bl = bias[tt * 16 + col];
#pragma unroll
    for (int reg = 0; reg < 4; reg++) {
      float ad = (float)add64[(size_t)ndc[reg] * 64 + tt * 16 + col];
      acc[tt][reg] += ad * inv[reg] + bl;
    }
  }

#pragma unroll
  for (int tt = 0; tt < TT; tt++)
#pragma unroll
    for (int reg = 0; reg < 4; reg++)
      ostage[w][(l >> 4) * 4 + reg][tt * 16 + col] = (_Float16)acc[tt][reg];
  __syncthreads();
#pragma unroll
  for (int i = 0; i < 2; i++) {
    int idx = i * 64 + l;
    int r = idx >> 3, q = idx & 7;
    int gn = nb + r;
    if (gn < N)
      *(uint4*)(outp + (size_t)gn * 64 + q * 8) = *(const uint4*)(&ostage[w][r][q * 8]);
  }
}

// ---------------- edge MLP: swapped MFMA, D=[hid x edge], b1 in C-init ----------
__global__ __launch_bounds__(256) void k_edge_mfma(
    const _Float16* __restrict__ h2, const int* __restrict__ src,
    const int* __restrict__ dst,
    const float* __restrict__ W1, const float* __restrict__ W2,
    const float* __restrict__ b1, const float* __restrict__ b2,
    float* __restrict__ out, int E) {
  const int gtid = blockIdx.x * blockDim.x + threadIdx.x;
  const int wave = gtid >> 6;
  const int nwaves = (gridDim.x * blockDim.x) >> 6;
  const int l = threadIdx.x & 63;
  const int col = l & 15;
  const int kb = (l >> 4) * 8;
  const int hb = (l >> 4) * 4;
  const int ngroups = (E + 15) / 16;
  const int gpw = (ngroups + nwaves - 1) / nwaves;
  const int g0 = wave * gpw;
  const int g1 = min(g0 + gpw, ngroups);
  if (g0 >= ngroups) return;

  f16x8 afrag[8][2];
#pragma unroll
  for (int tt = 0; tt < 8; tt++)
#pragma unroll
    for (int s = 0; s < 2; s++) {
      f16x8 bf;
#pragma unroll
      for (int e = 0; e < 8; e++)
        bf[e] = (_Float16)W1[(size_t)(s * 32 + kb + e) * 128 + tt * 16 + col];
      afrag[tt][s] = bf;
    }
  float4 c0[8], w2v[8];
#pragma unroll
  for (int tt = 0; tt < 8; tt++) {
    int hbase = tt * 16 + hb;
    c0[tt]  = make_float4(b1[hbase], b1[hbase + 1], b1[hbase + 2], b1[hbase + 3]);
    w2v[tt] = make_float4(W2[hbase], W2[hbase + 1], W2[hbase + 2], W2[hbase + 3]);
  }
  const float b2v = b2[0];

  auto ldrows = [&](int g, f16x8& a0, f16x8& a1) {
    int pos = g * 16 + col;
    if (pos >= E) pos = E - 1;
    int sp = src[pos], dp = dst[pos];
    f16x8 as0 = *(const f16x8*)(h2 + (size_t)sp * 64 + kb);
    f16x8 ad0 = *(const f16x8*)(h2 + (size_t)dp * 64 + kb);
    f16x8 as1 = *(const f16x8*)(h2 + (size_t)sp * 64 + 32 + kb);
    f16x8 ad1 = *(const f16x8*)(h2 + (size_t)dp * 64 + 32 + kb);
    a0 = as0 * ad0;
    a1 = as1 * ad1;
  };

  auto compute = [&](int g, f16x8 a0, f16x8 a1) {
    float psum = 0.f;
#pragma unroll
    for (int tt = 0; tt < 8; tt++) {
      f32x4 acc = {c0[tt].x, c0[tt].y, c0[tt].z, c0[tt].w};
      acc = __builtin_amdgcn_mfma_f32_16x16x32_f16(afrag[tt][0], a0, acc, 0, 0, 0);
      acc = __builtin_amdgcn_mfma_f32_16x16x32_f16(afrag[tt][1], a1, acc, 0, 0, 0);
      psum += fmaxf(acc[0], 0.f) * w2v[tt].x + fmaxf(acc[1], 0.f) * w2v[tt].y
            + fmaxf(acc[2], 0.f) * w2v[tt].z + fmaxf(acc[3], 0.f) * w2v[tt].w;
    }
    psum += __shfl_xor(psum, 16, 64);
    psum += __shfl_xor(psum, 32, 64);
    if (l < 16) {
      int epos = g * 16 + l;
      if (epos < E) out[epos] = psum + b2v;
    }
  };

  f16x8 a0, a1, na0, na1;
  ldrows(g0, a0, a1);
  for (int g = g0; g < g1; g++) {
    if (g + 1 < g1) ldrows(g + 1, na0, na1);
    compute(g, a0, a1);
    a0 = na0; a1 = na1;
  }
}

// ---------------- launch ----------------
extern "C" void kernel_launch(void* const* d_in, const int* in_sizes, int n_in,
                              void* d_out, int out_size, void* d_ws, size_t ws_size,
                              hipStream_t stream) {
  const float* x   = (const float*)d_in[0];
  const int*   ei  = (const int*)d_in[1];
  const float* Wl1 = (const float*)d_in[2];
  const float* bl1 = (const float*)d_in[3];
  const float* Wr1 = (const float*)d_in[4];
  const float* Wl2 = (const float*)d_in[5];
  const float* bl2 = (const float*)d_in[6];
  const float* Wr2 = (const float*)d_in[7];
  const float* W1  = (const float*)d_in[8];
  const float* b1  = (const float*)d_in[9];
  const float* W2  = (const float*)d_in[10];
  const float* b2  = (const float*)d_in[11];
  const int N = in_sizes[0] / 64;
  const int E = in_sizes[1] / 2;
  const int* src = ei;
  const int* dstp = ei + E;

  char* w = (char*)d_ws;
  size_t off = 0;
  auto alloc = [&](size_t bytes) -> void* {
    void* p = w + off;
    off = (off + bytes + 255) & ~(size_t)255;
    return p;
  };
  int*      deg      = (int*)alloc((size_t)N * 4);
  int*      row      = (int*)alloc((size_t)(N + 1) * 4);
  int*      ex       = (int*)alloc((size_t)N * 4);
  int*      bsum     = (int*)alloc(1024 * 4);
  int*      cbcursor = (int*)alloc(512 * 4);
  int*      srcs     = (int*)alloc((size_t)E * 4);
  unsigned long long* ep = (unsigned long long*)alloc((size_t)E * 8);
  _Float16* f16buf   = (_Float16*)alloc((size_t)N * 64 * 2);   // x16 -> g16 -> h2
  _Float16* agg16    = (_Float16*)alloc((size_t)N * 64 * 2);   // aggX -> aggG
  _Float16* h1_16    = (_Float16*)alloc((size_t)N * 128 * 2);

  const int ncb = (N + 255) >> 8;

  hipMemsetAsync(deg, 0, (size_t)N * 4, stream);
  int n4 = N * 16;
  int kag = (max(n4, E) + 255) / 256;
  kA_convert_hist<<<kag, 256, 0, stream>>>(x, f16buf, dstp, deg, n4, E);
  int nb = (N + 255) / 256;
  k_scan1<<<nb, 256, 0, stream>>>(deg, ex, bsum, N);
  k_scan2<<<1, 1024, 0, stream>>>(bsum, nb);
  k_scan3<<<nb, 256, 0, stream>>>(bsum, row, ex, cbcursor, N, E);
  k_coarse<<<256, 256, 0, stream>>>(src, dstp, cbcursor, ep, E);
  k_fine_sort<<<ncb, 256, 0, stream>>>(ep, row, srcs, N, E);

  int ngrid = (N + 63) / 64;
  int ggrid = (N * 8 + 255) / 256;
  k_gather16<<<ggrid, 256, 0, stream>>>(f16buf, row, srcs, agg16, N);
  k_h1g_mfma<<<ngrid, 256, 0, stream>>>(agg16, f16buf, Wl1, Wr1, bl1, Wl2, deg,
                                        h1_16, f16buf, N);
  k_gather16<<<ggrid, 256, 0, stream>>>(f16buf, row, srcs, agg16, N);
  k_h2_mfma<<<ngrid, 256, 0, stream>>>(h1_16, Wr2, bl2, agg16, deg, f16buf, N);
  k_edge_mfma<<<4096, 256, 0, stream>>>(f16buf, src, dstp, W1, W2, b1, b2,
                                        (float*)d_out, E);
}